// Round 5
// baseline (2257.505 us; speedup 1.0000x reference)
//
#include <hip/hip_runtime.h>
#include <stdint.h>

#define NB   4
#define NPTS 2048
#define NROWS (NB * NPTS)   // 8192
#define KNN  64
typedef unsigned long long u64;

// Sinkhorn in base-2 scaled domain: pot2 = pot * log2(e).
#define NEG_SCALE_L2E (-288.53900817779268f)  // -(1/eps)*log2(e)
#define TWO_SCALE_L2E (577.07801635558536f)

#define SWZ(i) ((i) + ((i) >> 5))   // LDS float4 swizzle: bank-spread groups
#define COLV_N (NPTS + NPTS / 32)   // 2112

// ---------- helpers ----------

__device__ __forceinline__ float wave_sum(float v) {
#pragma unroll
  for (int o = 32; o >= 1; o >>= 1) v += __shfl_xor(v, o);
  return v;
}
__device__ __forceinline__ float fexp2(float x) {
  float r; asm("v_exp_f32 %0, %1" : "=v"(r) : "v"(x)); return r;
}
__device__ __forceinline__ float flog2(float x) {
  float r; asm("v_log_f32 %0, %1" : "=v"(r) : "v"(x)); return r;
}
__device__ __forceinline__ float sqdist(const float4 a, const float4 c) {
  float dot = a.x * c.x + a.y * c.y + a.z * c.z;
  float d   = a.w + c.w - 2.0f * dot;
  return fmaxf(d, 0.0f);
}
__device__ __forceinline__ uint32_t rotl32(uint32_t x, uint32_t d) {
  return (x << d) | (x >> (32u - d));
}
__device__ __forceinline__ int mbcnt64(u64 m) {
  return __builtin_amdgcn_mbcnt_hi((uint32_t)(m >> 32),
         __builtin_amdgcn_mbcnt_lo((uint32_t)m, 0));
}
__device__ __forceinline__ float2 lse_merge(float2 A, float2 B) {
  float nm = fmaxf(A.x, B.x);
  float s  = fmaf(A.y, fexp2(A.x - nm), B.y * fexp2(B.x - nm));
  return make_float2(nm, s);
}
__device__ __forceinline__ float agent_ld(const float* p) {
  return __hip_atomic_load(p, __ATOMIC_RELAXED, __HIP_MEMORY_SCOPE_AGENT);
}
__device__ __forceinline__ void agent_st(float* p, float v) {
  __hip_atomic_store(p, v, __ATOMIC_RELAXED, __HIP_MEMORY_SCOPE_AGENT);
}

// Grid barrier: 256 co-resident blocks (grid<=CUs, LDS allows 2/CU => no deadlock).
__device__ __forceinline__ void gbar(uint32_t* cnt, uint32_t target) {
  __syncthreads();
  if (threadIdx.x == 0) {
    __hip_atomic_fetch_add(cnt, 1u, __ATOMIC_ACQ_REL, __HIP_MEMORY_SCOPE_AGENT);
    while (__hip_atomic_load(cnt, __ATOMIC_RELAXED, __HIP_MEMORY_SCOPE_AGENT) < target)
      __builtin_amdgcn_s_sleep(2);
    (void)__hip_atomic_load(cnt, __ATOMIC_ACQUIRE, __HIP_MEMORY_SCOPE_AGENT);
  }
  __syncthreads();
}

// ---------- kernels ----------

__global__ __launch_bounds__(256) void init_kernel(
    const float* __restrict__ preds, const float* __restrict__ inputs,
    float4* __restrict__ in4, float4* __restrict__ pr4,
    float* __restrict__ lu, float* __restrict__ lv) {
  int i = blockIdx.x * 256 + threadIdx.x;
  if (i >= NROWS) return;
  float ax = inputs[3 * i], ay = inputs[3 * i + 1], az = inputs[3 * i + 2];
  in4[i] = make_float4(ax, ay, az, ax * ax + ay * ay + az * az);
  float px = preds[3 * i], py = preds[3 * i + 1], pz = preds[3 * i + 2];
  pr4[i] = make_float4(px, py, pz, px * px + py * py + pz * pz);
  lu[i] = 0.0f;
  lv[i] = 0.0f;
}

// All 100 Sinkhorn half-steps + final assignment, one persistent launch.
// 256 blocks x 512 threads; block owns 32 rows; thread: 4 rows x 32 cols.
__global__ __launch_bounds__(512) void sink_fused(
    const float4* __restrict__ in4, const float4* __restrict__ pr4,
    float* __restrict__ lu, float* __restrict__ lv,
    float4* __restrict__ perm4, uint32_t* __restrict__ barcnt) {
  __shared__ float4 colv[COLV_N];      // 33.75 KB, swizzled
  __shared__ float2 part[64][33];      // 16.5 KB
  __shared__ float2 q16[16][33];
  __shared__ float2 q4v[4][33];
  __shared__ u64 upart[64][33];        // 16.9 KB (assign)
  __shared__ u64 uq16[16][33];
  __shared__ u64 uq4[4][33];

  int tid  = threadIdx.x;
  int rblk = blockIdx.x * 32;
  int base = rblk & ~(NPTS - 1);
  int tr   = tid & 7;                  // thread-row 0..7 (x4 rows)
  int g    = tid >> 3;                 // col-group 0..63 (32 cols)
  int cb   = g * 33;                   // swizzled base of group g

  uint32_t phase = 0;
  for (int it = 0; it < 100; ++it) {
    const float4* rp = (it & 1) ? pr4 : in4;
    const float4* cp = (it & 1) ? in4 : pr4;
    const float*  pin  = (it & 1) ? lu : lv;
    float*        pout = (it & 1) ? lv : lu;

    for (int i = tid; i < NPTS; i += 512) {
      float4 c = cp[base + i];
      colv[SWZ(i)] = make_float4(c.x, c.y, c.z,
                                 fmaf(c.w, NEG_SCALE_L2E, agent_ld(&pin[base + i])));
    }
    __syncthreads();

    int r0 = rblk + tr * 4;
    float4 a0 = rp[r0], a1 = rp[r0 + 1], a2 = rp[r0 + 2], a3 = rp[r0 + 3];
    float mx0 = -INFINITY, mx1 = -INFINITY, mx2 = -INFINITY, mx3 = -INFINITY;
    float s0 = 0.f, s1 = 0.f, s2 = 0.f, s3 = 0.f;
#pragma unroll 8
    for (int c = 0; c < 32; ++c) {
      float4 p = colv[cb + c];
      float y0 = fmaf(a0.x * p.x + a0.y * p.y + a0.z * p.z, TWO_SCALE_L2E, p.w);
      float y1 = fmaf(a1.x * p.x + a1.y * p.y + a1.z * p.z, TWO_SCALE_L2E, p.w);
      float y2 = fmaf(a2.x * p.x + a2.y * p.y + a2.z * p.z, TWO_SCALE_L2E, p.w);
      float y3 = fmaf(a3.x * p.x + a3.y * p.y + a3.z * p.z, TWO_SCALE_L2E, p.w);
      if (y0 > mx0 + 8.0f) { s0 *= fexp2(mx0 - y0); mx0 = y0; }
      s0 += fexp2(y0 - mx0);
      if (y1 > mx1 + 8.0f) { s1 *= fexp2(mx1 - y1); mx1 = y1; }
      s1 += fexp2(y1 - mx1);
      if (y2 > mx2 + 8.0f) { s2 *= fexp2(mx2 - y2); mx2 = y2; }
      s2 += fexp2(y2 - mx2);
      if (y3 > mx3 + 8.0f) { s3 *= fexp2(mx3 - y3); mx3 = y3; }
      s3 += fexp2(y3 - mx3);
    }
    part[g][tr * 4 + 0] = make_float2(mx0, s0);
    part[g][tr * 4 + 1] = make_float2(mx1, s1);
    part[g][tr * 4 + 2] = make_float2(mx2, s2);
    part[g][tr * 4 + 3] = make_float2(mx3, s3);
    __syncthreads();
    {
      int row = tid & 31, q = tid >> 5;   // 16 quads x 32 rows
      float2 P = lse_merge(lse_merge(part[4 * q][row], part[4 * q + 1][row]),
                           lse_merge(part[4 * q + 2][row], part[4 * q + 3][row]));
      q16[q][row] = P;
    }
    __syncthreads();
    if (tid < 128) {
      int row = tid & 31, h = tid >> 5;
      float2 P = lse_merge(lse_merge(q16[4 * h][row], q16[4 * h + 1][row]),
                           lse_merge(q16[4 * h + 2][row], q16[4 * h + 3][row]));
      q4v[h][row] = P;
    }
    __syncthreads();
    if (tid < 32) {
      float2 P = lse_merge(lse_merge(q4v[0][tid], q4v[1][tid]),
                           lse_merge(q4v[2][tid], q4v[3][tid]));
      float aw = rp[rblk + tid].w;
      agent_st(&pout[rblk + tid],
               -11.0f - (flog2(P.y) + P.x + NEG_SCALE_L2E * aw));
    }
    gbar(barcnt, 256u * (++phase));
  }

  // ---- assignment: argmax_m(logK2 + lv2[m]) per input row ----
  for (int i = tid; i < NPTS; i += 512) {
    float4 c = pr4[base + i];
    colv[SWZ(i)] = make_float4(c.x, c.y, c.z,
                               fmaf(c.w, NEG_SCALE_L2E, agent_ld(&lv[base + i])));
  }
  __syncthreads();
  {
    int r0 = rblk + tr * 4;
    float4 a0 = in4[r0], a1 = in4[r0 + 1], a2 = in4[r0 + 2], a3 = in4[r0 + 3];
    u64 b0 = 0, b1 = 0, b2 = 0, b3 = 0;
#pragma unroll 8
    for (int c = 0; c < 32; ++c) {
      float4 p = colv[cb + c];
      uint32_t mtag = (uint32_t)(2047 - (g * 32 + c));
      float y0 = fmaf(a0.x * p.x + a0.y * p.y + a0.z * p.z, TWO_SCALE_L2E, p.w);
      float y1 = fmaf(a1.x * p.x + a1.y * p.y + a1.z * p.z, TWO_SCALE_L2E, p.w);
      float y2 = fmaf(a2.x * p.x + a2.y * p.y + a2.z * p.z, TWO_SCALE_L2E, p.w);
      float y3 = fmaf(a3.x * p.x + a3.y * p.y + a3.z * p.z, TWO_SCALE_L2E, p.w);
      uint32_t u0 = __float_as_uint(y0); u0 = (u0 & 0x80000000u) ? ~u0 : (u0 | 0x80000000u);
      uint32_t u1 = __float_as_uint(y1); u1 = (u1 & 0x80000000u) ? ~u1 : (u1 | 0x80000000u);
      uint32_t u2 = __float_as_uint(y2); u2 = (u2 & 0x80000000u) ? ~u2 : (u2 | 0x80000000u);
      uint32_t u3 = __float_as_uint(y3); u3 = (u3 & 0x80000000u) ? ~u3 : (u3 | 0x80000000u);
      u64 p0 = ((u64)u0 << 32) | mtag; b0 = (p0 > b0) ? p0 : b0;
      u64 p1 = ((u64)u1 << 32) | mtag; b1 = (p1 > b1) ? p1 : b1;
      u64 p2 = ((u64)u2 << 32) | mtag; b2 = (p2 > b2) ? p2 : b2;
      u64 p3 = ((u64)u3 << 32) | mtag; b3 = (p3 > b3) ? p3 : b3;
    }
    upart[g][tr * 4 + 0] = b0; upart[g][tr * 4 + 1] = b1;
    upart[g][tr * 4 + 2] = b2; upart[g][tr * 4 + 3] = b3;
  }
  __syncthreads();
  {
    int row = tid & 31, q = tid >> 5;
    u64 A = upart[4 * q][row], B = upart[4 * q + 1][row];
    u64 C = upart[4 * q + 2][row], D = upart[4 * q + 3][row];
    u64 M = A > B ? A : B; u64 N = C > D ? C : D;
    uq16[q][row] = M > N ? M : N;
  }
  __syncthreads();
  if (tid < 128) {
    int row = tid & 31, h = tid >> 5;
    u64 A = uq16[4 * h][row], B = uq16[4 * h + 1][row];
    u64 C = uq16[4 * h + 2][row], D = uq16[4 * h + 3][row];
    u64 M = A > B ? A : B; u64 N = C > D ? C : D;
    uq4[h][row] = M > N ? M : N;
  }
  __syncthreads();
  if (tid < 32) {
    u64 A = uq4[0][tid], B = uq4[1][tid], C = uq4[2][tid], D = uq4[3][tid];
    u64 M = A > B ? A : B; u64 N = C > D ? C : D;
    u64 X = M > N ? M : N;
    int m = 2047 - (int)(X & 0xFFFFFFFFu);
    perm4[rblk + tid] = pr4[base + m];
  }
}

// Per row (one wave, 4 waves/block): top-65 via 256-bucket histogram on
// sqrt(d) (range [0,8), all buckets counted) with EXACT per-wave fallback
// (bit-pattern binary search) when histogram can't resolve (tail rows /
// bucket overflow). Then exact (bits,idx) ranking, threefry mask, loss.
__global__ __launch_bounds__(256) void knn_loss_kernel(
    const float4* __restrict__ in4, const float4* __restrict__ perm4,
    float* __restrict__ out) {
  __shared__ float4 colv[COLV_N];      // 33.75 KB
  __shared__ uint32_t hist[4][256];
  __shared__ u64 cand[4][96];
  __shared__ u64 sel[4][64];
  int tid  = threadIdx.x;
  int wid  = tid >> 6, lane = tid & 63;
  int row  = blockIdx.x * 4 + wid;
  int base = row & ~(NPTS - 1);

  for (int i = tid; i < NPTS; i += 256) colv[SWZ(i)] = in4[base + i];
  __syncthreads();

  int ri = row - base;
  float4 a = colv[SWZ(ri)];
  float dv[32];
#pragma unroll
  for (int t = 0; t < 32; ++t) {
    int i = (t << 6) | lane;
    dv[t] = sqdist(a, colv[SWZ(i)]);
  }

#pragma unroll
  for (int j = 0; j < 4; ++j) hist[wid][lane * 4 + j] = 0u;
  asm volatile("s_waitcnt lgkmcnt(0)" ::: "memory");
#pragma unroll
  for (int t = 0; t < 32; ++t) {
    int key = (int)fminf(sqrtf(dv[t]) * 32.0f, 255.0f);
    atomicAdd(&hist[wid][key], 1u);
  }
  asm volatile("s_waitcnt lgkmcnt(0)" ::: "memory");

  uint32_t h0 = hist[wid][lane * 4 + 0], h1 = hist[wid][lane * 4 + 1];
  uint32_t h2 = hist[wid][lane * 4 + 2], h3 = hist[wid][lane * 4 + 3];
  uint32_t s4 = h0 + h1 + h2 + h3;
  uint32_t cum = s4;
#pragma unroll
  for (int o = 1; o < 64; o <<= 1) {
    uint32_t n = __shfl_up(cum, o);
    if (lane >= o) cum += n;
  }
  u64 bal = __ballot(cum >= 65u);
  int Bstar = 255;
  uint32_t cnt_sel = 0;
  if (bal != 0) {
    int lstar = __ffsll(bal) - 1;
    uint32_t cpx = __shfl(cum - s4, lstar);
    uint32_t g0 = __shfl(h0, lstar), g1 = __shfl(h1, lstar);
    uint32_t g2 = __shfl(h2, lstar), g3 = __shfl(h3, lstar);
    if      (cpx + g0 >= 65u)           { Bstar = 4 * lstar;     cnt_sel = cpx + g0; }
    else if (cpx + g0 + g1 >= 65u)      { Bstar = 4 * lstar + 1; cnt_sel = cpx + g0 + g1; }
    else if (cpx + g0 + g1 + g2 >= 65u) { Bstar = 4 * lstar + 2; cnt_sel = cpx + g0 + g1 + g2; }
    else                                { Bstar = 4 * lstar + 3; cnt_sel = cpx + g0 + g1 + g2 + g3; }
  }
  bool exact = (bal == 0) || (cnt_sel > 96u);   // wave-uniform

  uint32_t T = 0u;
  if (exact) {
    uint32_t lo = 0u, hi = 0x7F7FFFFFu;
    while (lo < hi) {
      uint32_t mid = lo + ((hi - lo) >> 1);
      int c = 0;
#pragma unroll
      for (int t = 0; t < 32; ++t) c += __popcll(__ballot(__float_as_uint(dv[t]) <= mid));
      if (c >= 65) hi = mid; else lo = mid + 1;
    }
    T = lo;
  }

  // compact candidates via ballot + mbcnt offsets
  int pos = 0;
#pragma unroll
  for (int t = 0; t < 32; ++t) {
    bool pr;
    if (exact) {
      pr = (__float_as_uint(dv[t]) <= T);
    } else {
      int key = (int)fminf(sqrtf(dv[t]) * 32.0f, 255.0f);
      pr = (key <= Bstar);
    }
    u64 m = __ballot(pr);
    if (pr) {
      int idx = pos + mbcnt64(m);
      if (idx < 96)
        cand[wid][idx] = ((u64)__float_as_uint(dv[t]) << 32) | (uint32_t)((t << 6) | lane);
    }
    pos += __popcll(m);
  }
  int nc = pos < 96 ? pos : 96;

  // rank by (bits, idx); ranks 1..64 -> knn positions 0..63 (rank 0 = self)
  u64 mine0 = (lane < nc) ? cand[wid][lane] : ~0ull;
  u64 mine1 = (lane + 64 < nc) ? cand[wid][lane + 64] : ~0ull;
  int r0 = 0, r1 = 0;
  for (int j = 0; j < nc; ++j) {
    u64 cj = cand[wid][j];
    r0 += (cj < mine0) ? 1 : 0;
    r1 += (cj < mine1) ? 1 : 0;
  }
  if (lane < nc && r0 >= 1 && r0 <= 64) sel[wid][r0 - 1] = mine0;
  if (lane + 64 < nc && r1 >= 1 && r1 <= 64) sel[wid][r1 - 1] = mine1;
  u64 s = sel[wid][lane];
  float kd = __uint_as_float((uint32_t)(s >> 32));
  int   ki = (int)(s & 0xFFFFFFFFu);

  // prob (bit-exact float32 op order vs reference)
  const float C1 = (float)(0.05 * 0.05);
  const float C2 = (float)(2.0 * (0.5657 * 0.5657));
  const float C3 = (float)(0.5657 * 2.5066282746);
  float t2 = (kd / C1) / C2;
  float pr = expf(-t2) / C3;

  // jax.random.uniform(key(42), (4,2048,64)) : threefry2x32, bit-exact
  uint32_t gid = ((uint32_t)row << 6) | (uint32_t)lane;
  const uint32_t HALF = 262144u;
  bool lo2 = gid < HALF;
  uint32_t c0 = lo2 ? gid : (gid - HALF);
  uint32_t c1 = lo2 ? (gid + HALF) : gid;
  const uint32_t k0 = 0u, k1 = 42u;
  const uint32_t k2 = 0x1BD11BDAu ^ k0 ^ k1;
  uint32_t x0 = c0 + k0, x1 = c1 + k1;
#define TF_RND(rr) { x0 += x1; x1 = rotl32(x1, rr); x1 ^= x0; }
  TF_RND(13) TF_RND(15) TF_RND(26) TF_RND(6)
  x0 += k1; x1 += k2 + 1u;
  TF_RND(17) TF_RND(29) TF_RND(16) TF_RND(24)
  x0 += k2; x1 += k0 + 2u;
  TF_RND(13) TF_RND(15) TF_RND(26) TF_RND(6)
  x0 += k0; x1 += k1 + 3u;
  TF_RND(17) TF_RND(29) TF_RND(16) TF_RND(24)
  x0 += k1; x1 += k2 + 4u;
  TF_RND(13) TF_RND(15) TF_RND(26) TF_RND(6)
  x0 += k2; x1 += k0 + 5u;
#undef TF_RND
  uint32_t bits = lo2 ? x0 : x1;
  float u = __uint_as_float((bits >> 9) | 0x3F800000u) - 1.0f;

  bool msk = (u < pr);
  u64 bmask = __ballot(msk);
  int cnt = __popcll(bmask);
  if (cnt == 0 && lane == KNN - 1) msk = true;  // farthest fallback
  float num = (cnt == 0) ? 1.0f : (float)cnt;

  float4 nb = colv[SWZ(ki)];
  float4 pp = perm4[row];
  float dx = pp.x - nb.x, dy = pp.y - nb.y, dz = pp.z - nb.z;
  float dist = dx * dx + dy * dy + dz * dz;
  float contrib = msk ? dist : 0.0f;
  contrib = wave_sum(contrib);
  if (lane == 0) atomicAdd(out, contrib / num);
}

// ---------- launch ----------

extern "C" void kernel_launch(void* const* d_in, const int* in_sizes, int n_in,
                              void* d_out, int out_size, void* d_ws, size_t ws_size,
                              hipStream_t stream) {
  const float* preds  = (const float*)d_in[0];
  const float* inputs = (const float*)d_in[1];
  float* out = (float*)d_out;

  char* ws = (char*)d_ws;
  float4* in4   = (float4*)(ws);             // 131072 B
  float4* pr4   = (float4*)(ws + 131072);    // 131072 B
  float*  lu    = (float*)(ws + 262144);     // 32768 B (base-2 scaled)
  float*  lv    = (float*)(ws + 294912);     // 32768 B (base-2 scaled)
  float4* perm4 = (float4*)(ws + 327680);    // 131072 B
  uint32_t* barcnt = (uint32_t*)(ws + 458752);

  hipMemsetAsync(d_out, 0, (size_t)out_size * sizeof(float), stream);
  hipMemsetAsync(barcnt, 0, 64, stream);

  init_kernel<<<NROWS / 256, 256, 0, stream>>>(preds, inputs, in4, pr4, lu, lv);
  sink_fused<<<256, 512, 0, stream>>>(in4, pr4, lu, lv, perm4, barcnt);
  knn_loss_kernel<<<NROWS / 4, 256, 0, stream>>>(in4, perm4, out);
}

// Round 6
// 1782.740 us; speedup vs baseline: 1.2663x; 1.2663x over previous
//
#include <hip/hip_runtime.h>
#include <stdint.h>

#define NB   4
#define NPTS 2048
#define NROWS (NB * NPTS)   // 8192
#define KNN  64
typedef unsigned long long u64;

// Sinkhorn in base-2 scaled domain: pot2 = pot * log2(e).
#define NEG_SCALE_L2E (-288.53900817779268f)  // -(1/eps)*log2(e)
#define TWO_SCALE_L2E (577.07801635558536f)

#define SWZ(i) ((i) + ((i) >> 5))   // LDS float4 swizzle: bank-spread groups
#define COLV_N (NPTS + NPTS / 32)   // 2112

// ---------- helpers ----------

__device__ __forceinline__ float wave_sum(float v) {
#pragma unroll
  for (int o = 32; o >= 1; o >>= 1) v += __shfl_xor(v, o);
  return v;
}
__device__ __forceinline__ float fexp2(float x) {
  float r; asm("v_exp_f32 %0, %1" : "=v"(r) : "v"(x)); return r;
}
__device__ __forceinline__ float flog2(float x) {
  float r; asm("v_log_f32 %0, %1" : "=v"(r) : "v"(x)); return r;
}
__device__ __forceinline__ float sqdist(const float4 a, const float4 c) {
  float dot = a.x * c.x + a.y * c.y + a.z * c.z;
  float d   = a.w + c.w - 2.0f * dot;
  return fmaxf(d, 0.0f);
}
__device__ __forceinline__ uint32_t rotl32(uint32_t x, uint32_t d) {
  return (x << d) | (x >> (32u - d));
}
__device__ __forceinline__ int mbcnt64(u64 m) {
  return __builtin_amdgcn_mbcnt_hi((uint32_t)(m >> 32),
         __builtin_amdgcn_mbcnt_lo((uint32_t)m, 0));
}
__device__ __forceinline__ float2 lse_merge(float2 A, float2 B) {
  float nm = fmaxf(A.x, B.x);
  float s  = fmaf(A.y, fexp2(A.x - nm), B.y * fexp2(B.x - nm));
  return make_float2(nm, s);
}
__device__ __forceinline__ float agent_ld(const float* p) {
  return __hip_atomic_load(p, __ATOMIC_RELAXED, __HIP_MEMORY_SCOPE_AGENT);
}
__device__ __forceinline__ void agent_st(float* p, float v) {
  __hip_atomic_store(p, v, __ATOMIC_RELAXED, __HIP_MEMORY_SCOPE_AGENT);
}

// Per-batch hierarchical barrier. Batch has 128 blocks = 16 groups x 8.
// Monotonic counters (no reset): after phase p, each grp==8p, root==16p,
// rel==p. Group counters live on separate 128-B lines.
__device__ __forceinline__ void gbar_b(uint32_t* bb, int gi, uint32_t phase) {
  __syncthreads();
  if (threadIdx.x == 0) {
    uint32_t* grp  = bb + gi * 32;     // 128-B line per group
    uint32_t* root = bb + 512;         // own line
    uint32_t* rel  = bb + 544;         // own line
    uint32_t old = __hip_atomic_fetch_add(grp, 1u, __ATOMIC_ACQ_REL,
                                          __HIP_MEMORY_SCOPE_AGENT);
    if (old == 8u * phase - 1u) {      // last arriver in group
      uint32_t r = __hip_atomic_fetch_add(root, 1u, __ATOMIC_ACQ_REL,
                                          __HIP_MEMORY_SCOPE_AGENT);
      if (r == 16u * phase - 1u)       // last group: release
        __hip_atomic_store(rel, phase, __ATOMIC_RELEASE,
                           __HIP_MEMORY_SCOPE_AGENT);
    }
    while (__hip_atomic_load(rel, __ATOMIC_RELAXED,
                             __HIP_MEMORY_SCOPE_AGENT) < phase)
      __builtin_amdgcn_s_sleep(4);
    (void)__hip_atomic_load(rel, __ATOMIC_ACQUIRE, __HIP_MEMORY_SCOPE_AGENT);
  }
  __syncthreads();
}

// ---------- kernels ----------

__global__ __launch_bounds__(256) void init_kernel(
    const float* __restrict__ preds, const float* __restrict__ inputs,
    float4* __restrict__ in4, float4* __restrict__ pr4,
    float* __restrict__ lu, float* __restrict__ lv) {
  int i = blockIdx.x * 256 + threadIdx.x;
  if (i >= NROWS) return;
  float ax = inputs[3 * i], ay = inputs[3 * i + 1], az = inputs[3 * i + 2];
  in4[i] = make_float4(ax, ay, az, ax * ax + ay * ay + az * az);
  float px = preds[3 * i], py = preds[3 * i + 1], pz = preds[3 * i + 2];
  pr4[i] = make_float4(px, py, pz, px * px + py * py + pz * pz);
  lu[i] = 0.0f;
  lv[i] = 0.0f;
}

// All 100 Sinkhorn half-steps + final assignment, one persistent launch.
// 512 blocks x 512 threads (2/CU, 16 waves/CU; LDS 45.2 KB -> 3/CU capacity
// so co-residency of 512 is guaranteed). Block owns 16 rows; thread: 2 rows
// x 32 cols. Per-(row, col-group) op order identical to the R5 kernel.
__global__ __launch_bounds__(512) void sink_fused(
    const float4* __restrict__ in4, const float4* __restrict__ pr4,
    float* __restrict__ lu, float* __restrict__ lv,
    float4* __restrict__ perm4, uint32_t* __restrict__ barcnt) {
  __shared__ float4 colv[COLV_N];      // 33792 B, swizzled
  __shared__ float2 part[64][17];      // 8704 B
  __shared__ float2 q16[16][17];       // 2176 B
  __shared__ float2 q4v[4][17];        // 544 B   (total 45216 B)

  int tid   = threadIdx.x;
  int rblk  = blockIdx.x * 16;
  int base  = rblk & ~(NPTS - 1);
  int batch = blockIdx.x >> 7;         // 128 blocks per batch
  int gi    = blockIdx.x & 15;         // barrier group (8 blocks, stride 16)
  uint32_t* bb = barcnt + batch * 1024;
  int tr = tid & 7;                    // thread-row (x2 rows)
  int g  = tid >> 3;                   // col-group 0..63 (32 cols)
  int cb = g * 33;                     // SWZ(32g) base

  uint32_t phase = 0;
  for (int it = 0; it < 100; ++it) {
    const float4* rp = (it & 1) ? pr4 : in4;
    const float4* cp = (it & 1) ? in4 : pr4;
    const float*  pin  = (it & 1) ? lu : lv;
    float*        pout = (it & 1) ? lv : lu;

    for (int i = tid; i < NPTS; i += 512) {
      float4 c = cp[base + i];
      colv[SWZ(i)] = make_float4(c.x, c.y, c.z,
                                 fmaf(c.w, NEG_SCALE_L2E, agent_ld(&pin[base + i])));
    }
    __syncthreads();

    int r0 = rblk + tr * 2;
    float4 a0 = rp[r0], a1 = rp[r0 + 1];
    float mx0 = -INFINITY, mx1 = -INFINITY;
    float s0 = 0.f, s1 = 0.f;
#pragma unroll 8
    for (int c = 0; c < 32; ++c) {
      float4 p = colv[cb + c];
      float y0 = fmaf(a0.x * p.x + a0.y * p.y + a0.z * p.z, TWO_SCALE_L2E, p.w);
      float y1 = fmaf(a1.x * p.x + a1.y * p.y + a1.z * p.z, TWO_SCALE_L2E, p.w);
      if (y0 > mx0 + 8.0f) { s0 *= fexp2(mx0 - y0); mx0 = y0; }
      s0 += fexp2(y0 - mx0);
      if (y1 > mx1 + 8.0f) { s1 *= fexp2(mx1 - y1); mx1 = y1; }
      s1 += fexp2(y1 - mx1);
    }
    part[g][tr * 2 + 0] = make_float2(mx0, s0);
    part[g][tr * 2 + 1] = make_float2(mx1, s1);
    __syncthreads();

    if (tid < 256) {
      int row = tid & 15, q = tid >> 4;
      float2 P = lse_merge(lse_merge(part[4 * q][row], part[4 * q + 1][row]),
                           lse_merge(part[4 * q + 2][row], part[4 * q + 3][row]));
      q16[q][row] = P;
    }
    __syncthreads();
    if (tid < 64) {
      int row = tid & 15, h = tid >> 4;
      float2 P = lse_merge(lse_merge(q16[4 * h][row], q16[4 * h + 1][row]),
                           lse_merge(q16[4 * h + 2][row], q16[4 * h + 3][row]));
      q4v[h][row] = P;
    }
    __syncthreads();
    if (tid < 16) {
      float2 P = lse_merge(lse_merge(q4v[0][tid], q4v[1][tid]),
                           lse_merge(q4v[2][tid], q4v[3][tid]));
      float aw = rp[rblk + tid].w;
      agent_st(&pout[rblk + tid],
               -11.0f - (flog2(P.y) + P.x + NEG_SCALE_L2E * aw));
    }
    gbar_b(bb, gi, ++phase);
  }

  // ---- assignment: argmax_m(logK2 + lv2[m]) per input row ----
  u64* upart = (u64*)&part[0][0];      // reuse merge buffers as u64 [.][17]
  u64* uq16  = (u64*)&q16[0][0];
  u64* uq4   = (u64*)&q4v[0][0];

  for (int i = tid; i < NPTS; i += 512) {
    float4 c = pr4[base + i];
    colv[SWZ(i)] = make_float4(c.x, c.y, c.z,
                               fmaf(c.w, NEG_SCALE_L2E, agent_ld(&lv[base + i])));
  }
  __syncthreads();
  {
    int r0 = rblk + tr * 2;
    float4 a0 = in4[r0], a1 = in4[r0 + 1];
    u64 b0 = 0, b1 = 0;
#pragma unroll 8
    for (int c = 0; c < 32; ++c) {
      float4 p = colv[cb + c];
      uint32_t mtag = (uint32_t)(2047 - (g * 32 + c));
      float y0 = fmaf(a0.x * p.x + a0.y * p.y + a0.z * p.z, TWO_SCALE_L2E, p.w);
      float y1 = fmaf(a1.x * p.x + a1.y * p.y + a1.z * p.z, TWO_SCALE_L2E, p.w);
      uint32_t u0 = __float_as_uint(y0); u0 = (u0 & 0x80000000u) ? ~u0 : (u0 | 0x80000000u);
      uint32_t u1 = __float_as_uint(y1); u1 = (u1 & 0x80000000u) ? ~u1 : (u1 | 0x80000000u);
      u64 p0 = ((u64)u0 << 32) | mtag; b0 = (p0 > b0) ? p0 : b0;
      u64 p1 = ((u64)u1 << 32) | mtag; b1 = (p1 > b1) ? p1 : b1;
    }
    upart[g * 17 + tr * 2 + 0] = b0;
    upart[g * 17 + tr * 2 + 1] = b1;
  }
  __syncthreads();
  if (tid < 256) {
    int row = tid & 15, q = tid >> 4;
    u64 A = upart[(4 * q) * 17 + row],     B = upart[(4 * q + 1) * 17 + row];
    u64 C = upart[(4 * q + 2) * 17 + row], D = upart[(4 * q + 3) * 17 + row];
    u64 M = A > B ? A : B; u64 N = C > D ? C : D;
    uq16[q * 17 + row] = M > N ? M : N;
  }
  __syncthreads();
  if (tid < 64) {
    int row = tid & 15, h = tid >> 4;
    u64 A = uq16[(4 * h) * 17 + row],     B = uq16[(4 * h + 1) * 17 + row];
    u64 C = uq16[(4 * h + 2) * 17 + row], D = uq16[(4 * h + 3) * 17 + row];
    u64 M = A > B ? A : B; u64 N = C > D ? C : D;
    uq4[h * 17 + row] = M > N ? M : N;
  }
  __syncthreads();
  if (tid < 16) {
    u64 A = uq4[0 * 17 + tid], B = uq4[1 * 17 + tid];
    u64 C = uq4[2 * 17 + tid], D = uq4[3 * 17 + tid];
    u64 M = A > B ? A : B; u64 N = C > D ? C : D;
    u64 X = M > N ? M : N;
    int m = 2047 - (int)(X & 0xFFFFFFFFu);
    perm4[rblk + tid] = pr4[base + m];
  }
}

// Per row (one wave, 4 waves/block): top-65 via 256-bucket histogram on
// sqrt(d) with exact binary-search fallback; in4 read straight from
// L1/L2 (32 KB/batch, cache-resident). NO global atomics: per-row partial
// written to ws, summed by reduce_kernel.
__global__ __launch_bounds__(256) void knn_loss_kernel(
    const float4* __restrict__ in4, const float4* __restrict__ perm4,
    float* __restrict__ partials) {
  __shared__ uint32_t hist[4][256];
  __shared__ u64 cand[4][96];
  __shared__ u64 sel[4][64];
  int tid  = threadIdx.x;
  int wid  = tid >> 6, lane = tid & 63;
  int row  = blockIdx.x * 4 + wid;
  int base = row & ~(NPTS - 1);
  const float4* ip = in4 + base;
  float4 a = in4[row];

  float dv[32];
#pragma unroll
  for (int t = 0; t < 32; ++t) dv[t] = sqdist(a, ip[(t << 6) | lane]);

#pragma unroll
  for (int j = 0; j < 4; ++j) hist[wid][lane * 4 + j] = 0u;
  asm volatile("s_waitcnt lgkmcnt(0)" ::: "memory");
#pragma unroll
  for (int t = 0; t < 32; ++t) {
    int key = (int)fminf(sqrtf(dv[t]) * 32.0f, 255.0f);
    atomicAdd(&hist[wid][key], 1u);
  }
  asm volatile("s_waitcnt lgkmcnt(0)" ::: "memory");

  uint32_t h0 = hist[wid][lane * 4 + 0], h1 = hist[wid][lane * 4 + 1];
  uint32_t h2 = hist[wid][lane * 4 + 2], h3 = hist[wid][lane * 4 + 3];
  uint32_t s4 = h0 + h1 + h2 + h3;
  uint32_t cum = s4;
#pragma unroll
  for (int o = 1; o < 64; o <<= 1) {
    uint32_t n = __shfl_up(cum, o);
    if (lane >= o) cum += n;
  }
  u64 bal = __ballot(cum >= 65u);
  int Bstar = 255;
  uint32_t cnt_sel = 0;
  if (bal != 0) {
    int lstar = __ffsll(bal) - 1;
    uint32_t cpx = __shfl(cum - s4, lstar);
    uint32_t g0 = __shfl(h0, lstar), g1 = __shfl(h1, lstar);
    uint32_t g2 = __shfl(h2, lstar), g3 = __shfl(h3, lstar);
    if      (cpx + g0 >= 65u)           { Bstar = 4 * lstar;     cnt_sel = cpx + g0; }
    else if (cpx + g0 + g1 >= 65u)      { Bstar = 4 * lstar + 1; cnt_sel = cpx + g0 + g1; }
    else if (cpx + g0 + g1 + g2 >= 65u) { Bstar = 4 * lstar + 2; cnt_sel = cpx + g0 + g1 + g2; }
    else                                { Bstar = 4 * lstar + 3; cnt_sel = cpx + g0 + g1 + g2 + g3; }
  }
  bool exact = (bal == 0) || (cnt_sel > 96u);   // wave-uniform, rare

  uint32_t T = 0u;
  if (exact) {
    uint32_t lo = 0u, hi = 0x7F7FFFFFu;
    while (lo < hi) {
      uint32_t mid = lo + ((hi - lo) >> 1);
      int c = 0;
#pragma unroll
      for (int t = 0; t < 32; ++t) c += __popcll(__ballot(__float_as_uint(dv[t]) <= mid));
      if (c >= 65) hi = mid; else lo = mid + 1;
    }
    T = lo;
  }

  int pos = 0;
#pragma unroll
  for (int t = 0; t < 32; ++t) {
    bool pr;
    if (exact) {
      pr = (__float_as_uint(dv[t]) <= T);
    } else {
      int key = (int)fminf(sqrtf(dv[t]) * 32.0f, 255.0f);
      pr = (key <= Bstar);
    }
    u64 m = __ballot(pr);
    if (pr) {
      int idx = pos + mbcnt64(m);
      if (idx < 96)
        cand[wid][idx] = ((u64)__float_as_uint(dv[t]) << 32) | (uint32_t)((t << 6) | lane);
    }
    pos += __popcll(m);
  }
  int nc = pos < 96 ? pos : 96;

  u64 mine0 = (lane < nc) ? cand[wid][lane] : ~0ull;
  u64 mine1 = (lane + 64 < nc) ? cand[wid][lane + 64] : ~0ull;
  int r0 = 0, r1 = 0;
  for (int j = 0; j < nc; ++j) {
    u64 cj = cand[wid][j];
    r0 += (cj < mine0) ? 1 : 0;
    r1 += (cj < mine1) ? 1 : 0;
  }
  if (lane < nc && r0 >= 1 && r0 <= 64) sel[wid][r0 - 1] = mine0;
  if (lane + 64 < nc && r1 >= 1 && r1 <= 64) sel[wid][r1 - 1] = mine1;
  u64 s = sel[wid][lane];
  float kd = __uint_as_float((uint32_t)(s >> 32));
  int   ki = (int)(s & 0xFFFFFFFFu);

  const float C1 = (float)(0.05 * 0.05);
  const float C2 = (float)(2.0 * (0.5657 * 0.5657));
  const float C3 = (float)(0.5657 * 2.5066282746);
  float t2 = (kd / C1) / C2;
  float pr = expf(-t2) / C3;

  // jax.random.uniform(key(42), (4,2048,64)) : threefry2x32, bit-exact
  uint32_t gid = ((uint32_t)row << 6) | (uint32_t)lane;
  const uint32_t HALF = 262144u;
  bool lo2 = gid < HALF;
  uint32_t c0 = lo2 ? gid : (gid - HALF);
  uint32_t c1 = lo2 ? (gid + HALF) : gid;
  const uint32_t k0 = 0u, k1 = 42u;
  const uint32_t k2 = 0x1BD11BDAu ^ k0 ^ k1;
  uint32_t x0 = c0 + k0, x1 = c1 + k1;
#define TF_RND(rr) { x0 += x1; x1 = rotl32(x1, rr); x1 ^= x0; }
  TF_RND(13) TF_RND(15) TF_RND(26) TF_RND(6)
  x0 += k1; x1 += k2 + 1u;
  TF_RND(17) TF_RND(29) TF_RND(16) TF_RND(24)
  x0 += k2; x1 += k0 + 2u;
  TF_RND(13) TF_RND(15) TF_RND(26) TF_RND(6)
  x0 += k0; x1 += k1 + 3u;
  TF_RND(17) TF_RND(29) TF_RND(16) TF_RND(24)
  x0 += k1; x1 += k2 + 4u;
  TF_RND(13) TF_RND(15) TF_RND(26) TF_RND(6)
  x0 += k2; x1 += k0 + 5u;
#undef TF_RND
  uint32_t bits = lo2 ? x0 : x1;
  float u = __uint_as_float((bits >> 9) | 0x3F800000u) - 1.0f;

  bool msk = (u < pr);
  u64 bmask = __ballot(msk);
  int cnt = __popcll(bmask);
  if (cnt == 0 && lane == KNN - 1) msk = true;  // farthest fallback
  float num = (cnt == 0) ? 1.0f : (float)cnt;

  float4 nb = ip[ki];
  float4 pp = perm4[row];
  float dx = pp.x - nb.x, dy = pp.y - nb.y, dz = pp.z - nb.z;
  float dist = dx * dx + dy * dy + dz * dz;
  float contrib = msk ? dist : 0.0f;
  contrib = wave_sum(contrib);
  if (lane == 0) partials[row] = contrib / num;   // no atomics
}

// Sum 8192 per-row partials -> out[0]. One block.
__global__ __launch_bounds__(256) void reduce_kernel(
    const float* __restrict__ partials, float* __restrict__ out) {
  __shared__ float sm[4];
  int tid = threadIdx.x;
  float s = 0.0f;
  for (int i = tid; i < NROWS; i += 256) s += partials[i];
  s = wave_sum(s);
  if ((tid & 63) == 0) sm[tid >> 6] = s;
  __syncthreads();
  if (tid == 0) out[0] = (sm[0] + sm[1]) + (sm[2] + sm[3]);
}

// ---------- launch ----------

extern "C" void kernel_launch(void* const* d_in, const int* in_sizes, int n_in,
                              void* d_out, int out_size, void* d_ws, size_t ws_size,
                              hipStream_t stream) {
  const float* preds  = (const float*)d_in[0];
  const float* inputs = (const float*)d_in[1];
  float* out = (float*)d_out;

  char* ws = (char*)d_ws;
  float4* in4   = (float4*)(ws);             // 131072 B
  float4* pr4   = (float4*)(ws + 131072);    // 131072 B
  float*  lu    = (float*)(ws + 262144);     // 32768 B (base-2 scaled)
  float*  lv    = (float*)(ws + 294912);     // 32768 B (base-2 scaled)
  float4* perm4 = (float4*)(ws + 327680);    // 131072 B
  uint32_t* barcnt = (uint32_t*)(ws + 458752); // 16384 B (4 batches x 4 KB)
  float* partials  = (float*)(ws + 475136);    // 32768 B

  hipMemsetAsync(barcnt, 0, 16384, stream);

  init_kernel<<<NROWS / 256, 256, 0, stream>>>(preds, inputs, in4, pr4, lu, lv);
  sink_fused<<<512, 512, 0, stream>>>(in4, pr4, lu, lv, perm4, barcnt);
  knn_loss_kernel<<<NROWS / 4, 256, 0, stream>>>(in4, perm4, partials);
  reduce_kernel<<<1, 256, 0, stream>>>(partials, out);
}

// Round 7
// 745.735 us; speedup vs baseline: 3.0272x; 2.3906x over previous
//
#include <hip/hip_runtime.h>
#include <stdint.h>

#define NB   4
#define NPTS 2048
#define NROWS (NB * NPTS)   // 8192
#define KNN  64
typedef unsigned long long u64;

// Sinkhorn in base-2 scaled domain: pot2 = pot * log2(e).
#define NEG_SCALE_L2E (-288.53900817779268f)  // -(1/eps)*log2(e)
#define TWO_SCALE_L2E (577.07801635558536f)

#define SWZ(i) ((i) + ((i) >> 5))   // LDS float4 swizzle: bank-spread groups
#define COLV_N (NPTS + NPTS / 32)   // 2112

// ---------- helpers ----------

__device__ __forceinline__ float wave_sum(float v) {
#pragma unroll
  for (int o = 32; o >= 1; o >>= 1) v += __shfl_xor(v, o);
  return v;
}
__device__ __forceinline__ float fexp2(float x) {
  float r; asm("v_exp_f32 %0, %1" : "=v"(r) : "v"(x)); return r;
}
__device__ __forceinline__ float flog2(float x) {
  float r; asm("v_log_f32 %0, %1" : "=v"(r) : "v"(x)); return r;
}
__device__ __forceinline__ float sqdist(const float4 a, const float4 c) {
  float dot = a.x * c.x + a.y * c.y + a.z * c.z;
  float d   = a.w + c.w - 2.0f * dot;
  return fmaxf(d, 0.0f);
}
__device__ __forceinline__ uint32_t rotl32(uint32_t x, uint32_t d) {
  return (x << d) | (x >> (32u - d));
}
__device__ __forceinline__ int mbcnt64(u64 m) {
  return __builtin_amdgcn_mbcnt_hi((uint32_t)(m >> 32),
         __builtin_amdgcn_mbcnt_lo((uint32_t)m, 0));
}
__device__ __forceinline__ float2 lse_merge(float2 A, float2 B) {
  float nm = fmaxf(A.x, B.x);
  float s  = fmaf(A.y, fexp2(A.x - nm), B.y * fexp2(B.x - nm));
  return make_float2(nm, s);
}
// All cross-block data moves through agent-scope (sc1) atomics: they bypass
// the per-XCD L2 both ways, so the barrier needs NO acquire/release cache
// maintenance (no wbl2/inv). __syncthreads drains vmcnt before the arrival
// RMW, so pot stores are LLC-complete before the flag moves.
__device__ __forceinline__ float agent_ld(const float* p) {
  return __hip_atomic_load(p, __ATOMIC_RELAXED, __HIP_MEMORY_SCOPE_AGENT);
}
__device__ __forceinline__ void agent_st(float* p, float v) {
  __hip_atomic_store(p, v, __ATOMIC_RELAXED, __HIP_MEMORY_SCOPE_AGENT);
}

// Per-batch fully-RELAXED hierarchical barrier. 64 blocks = 8 groups x 8.
// Monotonic counters; group counters on separate 128-B lines.
__device__ __forceinline__ void gbar_b(uint32_t* bb, int gi, uint32_t phase) {
  __syncthreads();                     // drains vmcnt: pot stores complete
  if (threadIdx.x == 0) {
    uint32_t* grp  = bb + gi * 32;     // 8 groups, 128-B apart
    uint32_t* root = bb + 256;
    uint32_t* rel  = bb + 288;
    uint32_t old = __hip_atomic_fetch_add(grp, 1u, __ATOMIC_RELAXED,
                                          __HIP_MEMORY_SCOPE_AGENT);
    if (old == 8u * phase - 1u) {
      uint32_t r = __hip_atomic_fetch_add(root, 1u, __ATOMIC_RELAXED,
                                          __HIP_MEMORY_SCOPE_AGENT);
      if (r == 8u * phase - 1u)
        __hip_atomic_store(rel, phase, __ATOMIC_RELAXED,
                           __HIP_MEMORY_SCOPE_AGENT);
    }
    while (__hip_atomic_load(rel, __ATOMIC_RELAXED,
                             __HIP_MEMORY_SCOPE_AGENT) < phase)
      __builtin_amdgcn_s_sleep(1);
  }
  asm volatile("" ::: "memory");
  __syncthreads();
}

// ---------- kernels ----------

__global__ __launch_bounds__(256) void init_kernel(
    const float* __restrict__ preds, const float* __restrict__ inputs,
    float4* __restrict__ in4, float4* __restrict__ pr4,
    float* __restrict__ lu, float* __restrict__ lv) {
  int i = blockIdx.x * 256 + threadIdx.x;
  if (i >= NROWS) return;
  float ax = inputs[3 * i], ay = inputs[3 * i + 1], az = inputs[3 * i + 2];
  in4[i] = make_float4(ax, ay, az, ax * ax + ay * ay + az * az);
  float px = preds[3 * i], py = preds[3 * i + 1], pz = preds[3 * i + 2];
  pr4[i] = make_float4(px, py, pz, px * px + py * py + pz * pz);
  lu[i] = 0.0f;
  lv[i] = 0.0f;
}

// All 100 Sinkhorn half-steps + assignment. 256 blocks x 1024 threads,
// 1 block/CU (103 KB LDS) -> all blocks resident, no deadlock.
// Points staged in LDS ONCE (static across phases); per-phase global traffic
// is only the 8 KB pot vector via sc1. Block owns 32 rows; thread: 2 rows x
// 32 cols. Two-pass exact-max LSE (pass2 recomputes dot; no spills).
__global__ __launch_bounds__(1024, 4) void sink_fused(
    const float4* __restrict__ in4, const float4* __restrict__ pr4,
    float* __restrict__ lu, float* __restrict__ lv,
    float4* __restrict__ perm4, uint32_t* __restrict__ barcnt) {
  __shared__ float4 cin[COLV_N];       // 33792 B  (x,y,z, -K2*|c|^2)
  __shared__ float4 cpr[COLV_N];       // 33792 B
  __shared__ float  potv[NPTS];        // 8192 B
  __shared__ float2 part[64][33];      // 16896 B
  __shared__ float2 q32m[32][33];      // 8448 B
  __shared__ float2 q8m[8][33];        // 2112 B   (total 103232 B)

  int tid   = threadIdx.x;
  int blk   = blockIdx.x & 63;         // block within batch
  int batch = blockIdx.x >> 6;
  int base  = batch << 11;
  int rblk  = blk << 5;                // first row (batch-relative)
  int gi    = blk & 7;
  uint32_t* bb = barcnt + (batch << 9);  // 2 KB stride per batch
  int tr = tid & 15, g = tid >> 4;     // 16 thread-rows x 64 col-groups
  int cb = g * 33;                     // SWZ(32g)

  for (int i = tid; i < NPTS; i += 1024) {
    float4 c = in4[base + i];
    cin[SWZ(i)] = make_float4(c.x, c.y, c.z, NEG_SCALE_L2E * c.w);
    float4 p = pr4[base + i];
    cpr[SWZ(i)] = make_float4(p.x, p.y, p.z, NEG_SCALE_L2E * p.w);
  }
  __syncthreads();

  uint32_t phase = 0;
  for (int it = 0; it < 100; ++it) {
    const float*  pin  = (it & 1) ? lu : lv;
    float*        pout = (it & 1) ? lv : lu;
    const float4* crow = (it & 1) ? cpr : cin;
    const float4* ccol = (it & 1) ? cin : cpr;

    for (int i = tid; i < NPTS; i += 1024)
      potv[i] = agent_ld(&pin[base + i]);
    __syncthreads();

    int rl = rblk + tr * 2;
    float4 a0 = crow[SWZ(rl)];
    float4 a1 = crow[SWZ(rl + 1)];
    float mx0 = -INFINITY, mx1 = -INFINITY;
#pragma unroll
    for (int c = 0; c < 32; ++c) {
      float4 cv = ccol[cb + c];
      float wp = cv.w + potv[g * 32 + c];
      float d0 = a0.x * cv.x + a0.y * cv.y + a0.z * cv.z;
      float d1 = a1.x * cv.x + a1.y * cv.y + a1.z * cv.z;
      mx0 = fmaxf(mx0, fmaf(d0, TWO_SCALE_L2E, wp));
      mx1 = fmaxf(mx1, fmaf(d1, TWO_SCALE_L2E, wp));
    }
    float s0 = 0.f, s1 = 0.f;
#pragma unroll
    for (int c = 0; c < 32; ++c) {
      float4 cv = ccol[cb + c];
      float wp = cv.w + potv[g * 32 + c];
      float d0 = a0.x * cv.x + a0.y * cv.y + a0.z * cv.z;
      float d1 = a1.x * cv.x + a1.y * cv.y + a1.z * cv.z;
      s0 += fexp2(fmaf(d0, TWO_SCALE_L2E, wp - mx0));
      s1 += fexp2(fmaf(d1, TWO_SCALE_L2E, wp - mx1));
    }
    part[g][tr * 2 + 0] = make_float2(mx0, s0);
    part[g][tr * 2 + 1] = make_float2(mx1, s1);
    __syncthreads();
    {
      int row = tid & 31, q = tid >> 5;
      q32m[q][row] = lse_merge(part[2 * q][row], part[2 * q + 1][row]);
    }
    __syncthreads();
    if (tid < 256) {
      int row = tid & 31, h = tid >> 5;
      q8m[h][row] = lse_merge(lse_merge(q32m[4 * h][row], q32m[4 * h + 1][row]),
                              lse_merge(q32m[4 * h + 2][row], q32m[4 * h + 3][row]));
    }
    __syncthreads();
    if (tid < 32) {
      float2 P = q8m[0][tid];
#pragma unroll
      for (int k = 1; k < 8; ++k) P = lse_merge(P, q8m[k][tid]);
      float aw = crow[SWZ(rblk + tid)].w;   // already -K2*|a|^2
      agent_st(&pout[base + rblk + tid], -11.0f - (flog2(P.y) + P.x + aw));
    }
    gbar_b(bb, gi, ++phase);
  }

  // ---- assignment: argmax_m(logK2 + lv2[m]) per input row ----
  for (int i = tid; i < NPTS; i += 1024)
    potv[i] = agent_ld(&lv[base + i]);
  __syncthreads();
  u64* upart = (u64*)&part[0][0];
  u64* uq32  = (u64*)&q32m[0][0];
  u64* uq8   = (u64*)&q8m[0][0];
  {
    int rl = rblk + tr * 2;
    float4 a0 = cin[SWZ(rl)], a1 = cin[SWZ(rl + 1)];
    u64 b0 = 0, b1 = 0;
#pragma unroll
    for (int c = 0; c < 32; ++c) {
      float4 cv = cpr[cb + c];
      int m = g * 32 + c;
      float wp = cv.w + potv[m];
      float y0 = fmaf(a0.x * cv.x + a0.y * cv.y + a0.z * cv.z, TWO_SCALE_L2E, wp);
      float y1 = fmaf(a1.x * cv.x + a1.y * cv.y + a1.z * cv.z, TWO_SCALE_L2E, wp);
      uint32_t u0 = __float_as_uint(y0); u0 = (u0 & 0x80000000u) ? ~u0 : (u0 | 0x80000000u);
      uint32_t u1 = __float_as_uint(y1); u1 = (u1 & 0x80000000u) ? ~u1 : (u1 | 0x80000000u);
      u64 p0 = ((u64)u0 << 32) | (uint32_t)(2047 - m); b0 = p0 > b0 ? p0 : b0;
      u64 p1 = ((u64)u1 << 32) | (uint32_t)(2047 - m); b1 = p1 > b1 ? p1 : b1;
    }
    upart[g * 33 + tr * 2 + 0] = b0;
    upart[g * 33 + tr * 2 + 1] = b1;
  }
  __syncthreads();
  {
    int row = tid & 31, q = tid >> 5;
    u64 A = upart[(2 * q) * 33 + row], B = upart[(2 * q + 1) * 33 + row];
    uq32[q * 33 + row] = A > B ? A : B;
  }
  __syncthreads();
  if (tid < 256) {
    int row = tid & 31, h = tid >> 5;
    u64 A = uq32[(4 * h) * 33 + row],     B = uq32[(4 * h + 1) * 33 + row];
    u64 C = uq32[(4 * h + 2) * 33 + row], D = uq32[(4 * h + 3) * 33 + row];
    u64 M = A > B ? A : B; u64 N = C > D ? C : D;
    uq8[h * 33 + row] = M > N ? M : N;
  }
  __syncthreads();
  if (tid < 32) {
    u64 X = uq8[tid];
#pragma unroll
    for (int k = 1; k < 8; ++k) { u64 Y = uq8[k * 33 + tid]; X = Y > X ? Y : X; }
    int m = 2047 - (int)(X & 0xFFFFFFFFu);
    perm4[base + rblk + tid] = pr4[base + m];
  }
}

// Per row (one wave, 4 waves/block): top-65 via 256-bucket histogram on
// sqrt(d) with exact binary-search fallback; no global atomics.
__global__ __launch_bounds__(256) void knn_loss_kernel(
    const float4* __restrict__ in4, const float4* __restrict__ perm4,
    float* __restrict__ partials) {
  __shared__ uint32_t hist[4][256];
  __shared__ u64 cand[4][96];
  __shared__ u64 sel[4][64];
  int tid  = threadIdx.x;
  int wid  = tid >> 6, lane = tid & 63;
  int row  = blockIdx.x * 4 + wid;
  int base = row & ~(NPTS - 1);
  const float4* ip = in4 + base;
  float4 a = in4[row];

  float dv[32];
#pragma unroll
  for (int t = 0; t < 32; ++t) dv[t] = sqdist(a, ip[(t << 6) | lane]);

#pragma unroll
  for (int j = 0; j < 4; ++j) hist[wid][lane * 4 + j] = 0u;
  asm volatile("s_waitcnt lgkmcnt(0)" ::: "memory");
#pragma unroll
  for (int t = 0; t < 32; ++t) {
    int key = (int)fminf(sqrtf(dv[t]) * 32.0f, 255.0f);
    atomicAdd(&hist[wid][key], 1u);
  }
  asm volatile("s_waitcnt lgkmcnt(0)" ::: "memory");

  uint32_t h0 = hist[wid][lane * 4 + 0], h1 = hist[wid][lane * 4 + 1];
  uint32_t h2 = hist[wid][lane * 4 + 2], h3 = hist[wid][lane * 4 + 3];
  uint32_t s4 = h0 + h1 + h2 + h3;
  uint32_t cum = s4;
#pragma unroll
  for (int o = 1; o < 64; o <<= 1) {
    uint32_t n = __shfl_up(cum, o);
    if (lane >= o) cum += n;
  }
  u64 bal = __ballot(cum >= 65u);
  int Bstar = 255;
  uint32_t cnt_sel = 0;
  if (bal != 0) {
    int lstar = __ffsll(bal) - 1;
    uint32_t cpx = __shfl(cum - s4, lstar);
    uint32_t g0 = __shfl(h0, lstar), g1 = __shfl(h1, lstar);
    uint32_t g2 = __shfl(h2, lstar), g3 = __shfl(h3, lstar);
    if      (cpx + g0 >= 65u)           { Bstar = 4 * lstar;     cnt_sel = cpx + g0; }
    else if (cpx + g0 + g1 >= 65u)      { Bstar = 4 * lstar + 1; cnt_sel = cpx + g0 + g1; }
    else if (cpx + g0 + g1 + g2 >= 65u) { Bstar = 4 * lstar + 2; cnt_sel = cpx + g0 + g1 + g2; }
    else                                { Bstar = 4 * lstar + 3; cnt_sel = cpx + g0 + g1 + g2 + g3; }
  }
  bool exact = (bal == 0) || (cnt_sel > 96u);   // wave-uniform, rare

  uint32_t T = 0u;
  if (exact) {
    uint32_t lo = 0u, hi = 0x7F7FFFFFu;
    while (lo < hi) {
      uint32_t mid = lo + ((hi - lo) >> 1);
      int c = 0;
#pragma unroll
      for (int t = 0; t < 32; ++t) c += __popcll(__ballot(__float_as_uint(dv[t]) <= mid));
      if (c >= 65) hi = mid; else lo = mid + 1;
    }
    T = lo;
  }

  int pos = 0;
#pragma unroll
  for (int t = 0; t < 32; ++t) {
    bool pr;
    if (exact) {
      pr = (__float_as_uint(dv[t]) <= T);
    } else {
      int key = (int)fminf(sqrtf(dv[t]) * 32.0f, 255.0f);
      pr = (key <= Bstar);
    }
    u64 m = __ballot(pr);
    if (pr) {
      int idx = pos + mbcnt64(m);
      if (idx < 96)
        cand[wid][idx] = ((u64)__float_as_uint(dv[t]) << 32) | (uint32_t)((t << 6) | lane);
    }
    pos += __popcll(m);
  }
  int nc = pos < 96 ? pos : 96;

  u64 mine0 = (lane < nc) ? cand[wid][lane] : ~0ull;
  u64 mine1 = (lane + 64 < nc) ? cand[wid][lane + 64] : ~0ull;
  int r0 = 0, r1 = 0;
  for (int j = 0; j < nc; ++j) {
    u64 cj = cand[wid][j];
    r0 += (cj < mine0) ? 1 : 0;
    r1 += (cj < mine1) ? 1 : 0;
  }
  if (lane < nc && r0 >= 1 && r0 <= 64) sel[wid][r0 - 1] = mine0;
  if (lane + 64 < nc && r1 >= 1 && r1 <= 64) sel[wid][r1 - 1] = mine1;
  u64 s = sel[wid][lane];
  float kd = __uint_as_float((uint32_t)(s >> 32));
  int   ki = (int)(s & 0xFFFFFFFFu);

  const float C1 = (float)(0.05 * 0.05);
  const float C2 = (float)(2.0 * (0.5657 * 0.5657));
  const float C3 = (float)(0.5657 * 2.5066282746);
  float t2 = (kd / C1) / C2;
  float pr = expf(-t2) / C3;

  // jax.random.uniform(key(42), (4,2048,64)) : threefry2x32, bit-exact
  uint32_t gid = ((uint32_t)row << 6) | (uint32_t)lane;
  const uint32_t HALF = 262144u;
  bool lo2 = gid < HALF;
  uint32_t c0 = lo2 ? gid : (gid - HALF);
  uint32_t c1 = lo2 ? (gid + HALF) : gid;
  const uint32_t k0 = 0u, k1 = 42u;
  const uint32_t k2 = 0x1BD11BDAu ^ k0 ^ k1;
  uint32_t x0 = c0 + k0, x1 = c1 + k1;
#define TF_RND(rr) { x0 += x1; x1 = rotl32(x1, rr); x1 ^= x0; }
  TF_RND(13) TF_RND(15) TF_RND(26) TF_RND(6)
  x0 += k1; x1 += k2 + 1u;
  TF_RND(17) TF_RND(29) TF_RND(16) TF_RND(24)
  x0 += k2; x1 += k0 + 2u;
  TF_RND(13) TF_RND(15) TF_RND(26) TF_RND(6)
  x0 += k0; x1 += k1 + 3u;
  TF_RND(17) TF_RND(29) TF_RND(16) TF_RND(24)
  x0 += k1; x1 += k2 + 4u;
  TF_RND(13) TF_RND(15) TF_RND(26) TF_RND(6)
  x0 += k2; x1 += k0 + 5u;
#undef TF_RND
  uint32_t bits = lo2 ? x0 : x1;
  float u = __uint_as_float((bits >> 9) | 0x3F800000u) - 1.0f;

  bool msk = (u < pr);
  u64 bmask = __ballot(msk);
  int cnt = __popcll(bmask);
  if (cnt == 0 && lane == KNN - 1) msk = true;  // farthest fallback
  float num = (cnt == 0) ? 1.0f : (float)cnt;

  float4 nb = ip[ki];
  float4 pp = perm4[row];
  float dx = pp.x - nb.x, dy = pp.y - nb.y, dz = pp.z - nb.z;
  float dist = dx * dx + dy * dy + dz * dz;
  float contrib = msk ? dist : 0.0f;
  contrib = wave_sum(contrib);
  if (lane == 0) partials[row] = contrib / num;
}

// Sum 8192 per-row partials -> out[0]. One block.
__global__ __launch_bounds__(256) void reduce_kernel(
    const float* __restrict__ partials, float* __restrict__ out) {
  __shared__ float sm[4];
  int tid = threadIdx.x;
  float s = 0.0f;
  for (int i = tid; i < NROWS; i += 256) s += partials[i];
  s = wave_sum(s);
  if ((tid & 63) == 0) sm[tid >> 6] = s;
  __syncthreads();
  if (tid == 0) out[0] = (sm[0] + sm[1]) + (sm[2] + sm[3]);
}

// ---------- launch ----------

extern "C" void kernel_launch(void* const* d_in, const int* in_sizes, int n_in,
                              void* d_out, int out_size, void* d_ws, size_t ws_size,
                              hipStream_t stream) {
  const float* preds  = (const float*)d_in[0];
  const float* inputs = (const float*)d_in[1];
  float* out = (float*)d_out;

  char* ws = (char*)d_ws;
  float4* in4   = (float4*)(ws);             // 131072 B
  float4* pr4   = (float4*)(ws + 131072);    // 131072 B
  float*  lu    = (float*)(ws + 262144);     // 32768 B (base-2 scaled)
  float*  lv    = (float*)(ws + 294912);     // 32768 B (base-2 scaled)
  float4* perm4 = (float4*)(ws + 327680);    // 131072 B
  uint32_t* barcnt = (uint32_t*)(ws + 458752); // 8192 B (4 batches x 2 KB)
  float* partials  = (float*)(ws + 466944);    // 32768 B

  hipMemsetAsync(barcnt, 0, 8192, stream);

  init_kernel<<<NROWS / 256, 256, 0, stream>>>(preds, inputs, in4, pr4, lu, lv);
  sink_fused<<<256, 1024, 0, stream>>>(in4, pr4, lu, lv, perm4, barcnt);
  knn_loss_kernel<<<NROWS / 4, 256, 0, stream>>>(in4, perm4, partials);
  reduce_kernel<<<1, 256, 0, stream>>>(partials, out);
}